// Round 9
// baseline (127.881 us; speedup 1.0000x reference)
//
#include <hip/hip_runtime.h>

// TaylorFeatureMap: x (2,16,2048,64) fp32 -> out (2,16,2048,2145) fp32
// Row layout per vector v:
//   [0]        = 1
//   [1..64]    = x[i] / 64^0.25
//   [65..128]  = x[i]^2 / (8*sqrt(2))
//   [129..2144]= x[i]*x[j] / 8, (i,j) = triu_indices(64, k=1) row-major
//
// R8 = R7 retry: R2 skeleton EXACTLY (measured best, 114.1 µs) + ONE change:
// non-temporal output stores. __builtin_nontemporal_store requires a NATIVE
// vector type (clang ext_vector), not HIP's float4 class -> use f32x4 alias.
// Theory: the 562 MB streaming write churns the 32 MB writeback L2
// (allocate+evict per line, competing with x reads, stretching store
// retirement); nt = no-allocate/early-evict stream.

#define D 64
#define ROW 2145
#define OFFD_BASE 129
#define RPB 4                      // rows per block (= waves per block)
#define NF4 (RPB * ROW / 4)        // 2145 float4 per block

typedef float f32x4 __attribute__((ext_vector_type(4)));

__global__ __launch_bounds__(256) void taylor_fm_kernel(
    const float* __restrict__ x, float* __restrict__ out) {
    __shared__ __align__(16) float buf[RPB * ROW];   // 34,320 B

    const int wave = threadIdx.x >> 6;
    const int lane = threadIdx.x & 63;
    const int row  = blockIdx.x * RPB + wave;

    const float xl = x[(size_t)row * D + lane];

    const float inv_rrd   = 0.35355339059327373f;   // 1/64^0.25
    const float inv_rd_r2 = 0.08838834764831845f;   // 1/(8*sqrt(2))

    float* brow = buf + wave * ROW;
    if (lane == 0) brow[0] = 1.0f;
    brow[1 + lane]  = xl * inv_rrd;
    brow[65 + lane] = xl * xl * inv_rd_r2;

    // Pre-scale by exact pow2 1/8 so (x_i/8)*x_j == (x_i*x_j)/8 bit-exactly.
    const float xls = xl * 0.125f;

    float* tri = brow + OFFD_BASE;
#pragma unroll
    for (int i = 0; i < 63; ++i) {
        const int Ci = (i * (127 - i)) >> 1;        // start of row i's segment
        float xi = __uint_as_float(
            __builtin_amdgcn_readlane(__float_as_uint(xls), i));
        if (lane > i) {
            tri[Ci - i - 1 + lane] = xi * xl;
        }
    }

    __syncthreads();

    // Dense aligned float4 stream: 2145 float4 per block, NON-TEMPORAL.
    const f32x4* b4 = reinterpret_cast<const f32x4*>(buf);
    f32x4* o4 = reinterpret_cast<f32x4*>(out + (size_t)blockIdx.x * (RPB * ROW));
    int q = threadIdx.x;
#pragma unroll
    for (int k = 0; k < 8; ++k, q += 256) {
        __builtin_nontemporal_store(b4[q], &o4[q]);
    }
    if (q < NF4) {                 // tail: 2145 - 8*256 = 97 float4
        __builtin_nontemporal_store(b4[q], &o4[q]);
    }
}

extern "C" void kernel_launch(void* const* d_in, const int* in_sizes, int n_in,
                              void* d_out, int out_size, void* d_ws, size_t ws_size,
                              hipStream_t stream) {
    const float* x = (const float*)d_in[0];
    float* out = (float*)d_out;
    int nrows = in_sizes[0] / D;        // 65536
    taylor_fm_kernel<<<nrows / RPB, 256, 0, stream>>>(x, out);
}

// Round 10
// 115.453 us; speedup vs baseline: 1.1076x; 1.1076x over previous
//
#include <hip/hip_runtime.h>

// TaylorFeatureMap: x (2,16,2048,64) fp32 -> out (2,16,2048,2145) fp32
// Row layout per vector v:
//   [0]        = 1
//   [1..64]    = x[i] / 64^0.25
//   [65..128]  = x[i]^2 / (8*sqrt(2))
//   [129..2144]= x[i]*x[j] / 8, (i,j) = triu_indices(64, k=1) row-major
//
// R9 = R2 skeleton EXACTLY (measured best, 114.1 µs) + ONE change: the
// store phase is split head/body/tail so every bulk wave-store is 128B
// cache-line aligned. Chunk = 34,320 B != 0 mod 128, so R2's stores each
// straddled lines: 9 line-requests per 1024B wave-store instead of 8
// (+12.5% TCC write transactions). If TCC request rate is what saturates
// at the fill kernel's 6.6 TB/s, alignment recovers ~0.7 TB/s.
// head_f4 = (8 - bid%8)%8, tail_f4 = (bid+1)%8  (2145 = 8*268+1).
// nt stores NOT used (R8: regressed; L2 writeback helps).

#define D 64
#define ROW 2145
#define OFFD_BASE 129
#define RPB 4                      // rows per block (= waves per block)
#define NF4 (RPB * ROW / 4)        // 2145 float4 per block

__global__ __launch_bounds__(256) void taylor_fm_kernel(
    const float* __restrict__ x, float* __restrict__ out) {
    __shared__ __align__(16) float buf[RPB * ROW];   // 34,320 B

    const int wave = threadIdx.x >> 6;
    const int lane = threadIdx.x & 63;
    const int row  = blockIdx.x * RPB + wave;

    const float xl = x[(size_t)row * D + lane];

    const float inv_rrd   = 0.35355339059327373f;   // 1/64^0.25
    const float inv_rd_r2 = 0.08838834764831845f;   // 1/(8*sqrt(2))

    float* brow = buf + wave * ROW;
    if (lane == 0) brow[0] = 1.0f;
    brow[1 + lane]  = xl * inv_rrd;
    brow[65 + lane] = xl * xl * inv_rd_r2;

    // Pre-scale by exact pow2 1/8 so (x_i/8)*x_j == (x_i*x_j)/8 bit-exactly.
    const float xls = xl * 0.125f;

    float* tri = brow + OFFD_BASE;
#pragma unroll
    for (int i = 0; i < 63; ++i) {
        const int Ci = (i * (127 - i)) >> 1;        // start of row i's segment
        float xi = __uint_as_float(
            __builtin_amdgcn_readlane(__float_as_uint(xls), i));
        if (lane > i) {
            tri[Ci - i - 1 + lane] = xi * xl;
        }
    }

    __syncthreads();

    // Store phase: head (to 128B boundary) + line-aligned body + tail.
    const float4* b4 = reinterpret_cast<const float4*>(buf);
    float4* o4 = reinterpret_cast<float4*>(out + (size_t)blockIdx.x * (RPB * ROW));

    const int head_f4 = (8 - (blockIdx.x & 7)) & 7;     // 0..7
    const int tail_f4 = (blockIdx.x + 1) & 7;           // 0..7
    const int body_end = NF4 - tail_f4;                 // body: [head_f4, body_end)

    if ((int)threadIdx.x < head_f4) {
        o4[threadIdx.x] = b4[threadIdx.x];
    }
    if ((int)threadIdx.x < tail_f4) {
        o4[body_end + threadIdx.x] = b4[body_end + threadIdx.x];
    }

    int q = head_f4 + threadIdx.x;
    // body >= 2131 -> every thread does 8 full iterations (max tid 255 +
    // 7*256 = 2047 < 2131), then at most one more.
#pragma unroll
    for (int k = 0; k < 8; ++k, q += 256) {
        o4[q] = b4[q];
    }
    if (q < body_end) {
        o4[q] = b4[q];
    }
}

extern "C" void kernel_launch(void* const* d_in, const int* in_sizes, int n_in,
                              void* d_out, int out_size, void* d_ws, size_t ws_size,
                              hipStream_t stream) {
    const float* x = (const float*)d_in[0];
    float* out = (float*)d_out;
    int nrows = in_sizes[0] / D;        // 65536
    taylor_fm_kernel<<<nrows / RPB, 256, 0, stream>>>(x, out);
}